// Round 11
// baseline (54.493 us; speedup 1.0000x reference)
//
#include <hip/hip_runtime.h>
#include <math.h>

#define GS 8
#define HC 60
#define WC 80
#define NN 4800      // HC*WC
#define CC 64
#define BB 2
#define HIMG 480
#define WIMG 640
#define EPSF 1e-8f
#define NTILES 75    // 4800 / 64
#define TGN 8        // column-split groups
#define BIGF 1e30f

typedef __attribute__((ext_vector_type(8))) short short8v;  // 8 bf16 = 4 VGPR
typedef __attribute__((ext_vector_type(4))) float f32x4;

__device__ __forceinline__ unsigned short f2bf(float f) {
    unsigned u = __float_as_uint(f);
    u += 0x7FFFu + ((u >> 16) & 1u);      // RNE
    return (unsigned short)(u >> 16);
}

// ============ k_pre: cvt (blocks 0..299) | per-cell wave prep (blocks 300..2699) ============
__global__ __launch_bounds__(256) void k_pre(
    const float* __restrict__ desc1, const float* __restrict__ desc2,
    const float* __restrict__ homo12, const float* __restrict__ homo21,
    unsigned short* __restrict__ d1bf, unsigned short* __restrict__ d2bf,
    float* __restrict__ posim, float* __restrict__ matchm,
    float* __restrict__ biasf, int* __restrict__ neighpk,
    unsigned int* __restrict__ negbits)
{
    __shared__ unsigned short tile[CC][65];
    int bid = blockIdx.x;
    int tid = threadIdx.x;

    if (bid < 2 * BB * NTILES) {
        // ---- convert fp32 [b][ch][cell] -> bf16 [b][cell][ch] ----
        int arr = bid / (BB * NTILES);
        int rem = bid % (BB * NTILES);
        int b = rem / NTILES;
        int t = rem % NTILES;
        int c0 = t * 64;
        const float* in = arr ? desc2 : desc1;
        unsigned short* out = arr ? d2bf : d1bf;
        int w = tid >> 6, l = tid & 63;
        #pragma unroll
        for (int k = 0; k < 16; k++) {
            int ch = k * 4 + w;
            tile[ch][l] = f2bf(in[((size_t)(b * CC + ch)) * NN + c0 + l]);
        }
        __syncthreads();
        #pragma unroll
        for (int k = 0; k < 16; k++) {
            int cell = k * 4 + w;
            out[((size_t)b * NN + c0 + cell) * CC + l] = tile[l][cell];
        }
        return;
    }

    // ---- per-cell: one wave per cell ----
    int sub = bid - 2 * BB * NTILES;      // 0..2399
    int wv = tid >> 6, lane = tid & 63;
    int idx = sub * 4 + wv;               // 0..9599
    int b = idx / NN, r = idx - b * NN;
    int ci = r / WC, cj = r - ci * WC;

    // visibility: lane = pixel (di,dj) of the 8x8 cell
    int allv;
    {
        const float* h = homo21 + b * 9;
        int di = lane >> 3, dj = lane & 7;
        float y = (float)(ci * 8 + di);
        float x = (float)(cj * 8 + dj);
        float qx = h[0]*x + h[1]*y + h[2];
        float qy = h[3]*x + h[4]*y + h[5];
        float qw = h[6]*x + h[7]*y + h[8];
        float px = qx / (qw + EPSF);
        float py = qy / (qw + EPSF);
        float y0 = floorf(py), x0 = floorf(px);
        float ty = py - y0,   tx = px - x0;
        float fyv = ((y0 >= 0.0f && y0 <= (float)(HIMG-1)) ? (1.0f-ty) : 0.0f)
                  + ((y0+1.0f >= 0.0f && y0+1.0f <= (float)(HIMG-1)) ? ty : 0.0f);
        float fxv = ((x0 >= 0.0f && x0 <= (float)(WIMG-1)) ? (1.0f-tx) : 0.0f)
                  + ((x0+1.0f >= 0.0f && x0+1.0f <= (float)(WIMG-1)) ? tx : 0.0f);
        int ok = (fyv > 0.0f && fxv > 0.0f) ? 1 : 0;
        allv = __all(ok);
    }

    // warp + bilinear setup (all lanes redundantly, uniform)
    const float* h = homo12 + b * 9;
    float xx = cj * 8.0f + 3.5f;
    float yy = ci * 8.0f + 3.5f;
    float qx = h[0]*xx + h[1]*yy + h[2];
    float qy = h[3]*xx + h[4]*yy + h[5];
    float qw = h[6]*xx + h[7]*yy + h[8];
    float wx = qx / (qw + EPSF);
    float wy = qy / (qw + EPSF);
    float dy = (wy - 4.0f + 0.5f) / 8.0f;
    float dx = (wx - 4.0f + 0.5f) / 8.0f;

    float y0f = floorf(dy), x0f = floorf(dx);
    float fy = dy - y0f, fx = dx - x0f;
    float y1f = y0f + 1.0f, x1f = x0f + 1.0f;
    bool v0y = (y0f >= 0.0f && y0f <= (float)(HC-1));
    bool v1y = (y1f >= 0.0f && y1f <= (float)(HC-1));
    bool v0x = (x0f >= 0.0f && x0f <= (float)(WC-1));
    bool v1x = (x1f >= 0.0f && x1f <= (float)(WC-1));
    float w00 = (1.0f-fy)*(1.0f-fx); if (!(v0y && v0x)) w00 = 0.0f;
    float w01 = (1.0f-fy)*fx;        if (!(v0y && v1x)) w01 = 0.0f;
    float w10 = fy*(1.0f-fx);        if (!(v1y && v0x)) w10 = 0.0f;
    float w11 = fy*fx;               if (!(v1y && v1x)) w11 = 0.0f;
    int yc0 = (int)fminf(fmaxf(y0f, 0.0f), (float)(HC-1));
    int yc1 = (int)fminf(fmaxf(y1f, 0.0f), (float)(HC-1));
    int xc0 = (int)fminf(fmaxf(x0f, 0.0f), (float)(WC-1));
    int xc1 = (int)fminf(fmaxf(x1f, 0.0f), (float)(WC-1));
    int o00 = yc0*WC + xc0, o01 = yc0*WC + xc1;
    int o10 = yc1*WC + xc0, o11 = yc1*WC + xc1;

    // lane = channel
    int ch = lane;
    const float* d2b = desc2 + (size_t)b * CC * NN;
    const float* p = d2b + ch * NN;
    float wvl = w00*p[o00] + w01*p[o01] + w10*p[o10] + w11*p[o11];
    float s2 = wvl * wvl;
    float sd = desc1[((size_t)(b * CC + ch)) * NN + r] * wvl;
    #pragma unroll
    for (int off = 1; off < 64; off <<= 1) {
        s2 += __shfl_xor(s2, off);
        sd += __shfl_xor(sd, off);
    }

    if (lane == 0) {
        biasf[idx] = allv ? 16.0f : 8.0f;
        matchm[idx] = (wy >= 0.0f && wy <= (float)(HIMG-1) &&
                       wx >= 0.0f && wx <= (float)(WIMG-1)) ? 1.0f : 0.0f;
        float dot = sd / (sqrtf(s2) + EPSF);
        posim[idx] = sqrtf(fmaxf(2.0f - 2.0f*dot, EPSF));

        // top-4 nearest grid centers -> packed bbox mask
        int i0 = (int)floorf(dy);
        int j0 = (int)floorf(dx);
        int ilo = i0 - 1; if (ilo < 0) ilo = 0; if (ilo > HC-4) ilo = HC-4;
        int jlo = j0 - 1; if (jlo < 0) jlo = 0; if (jlo > WC-4) jlo = WC-4;
        float bd0=3e38f, bd1=3e38f, bd2=3e38f, bd3=3e38f;
        int   id0=0,     id1=0,     id2=0,     id3=0;
        #pragma unroll
        for (int a = 0; a < 4; a++) {
            float cy = (float)(ilo + a) * 8.0f + 3.5f;
            float ddy = wy - cy;
            float ddy2 = ddy * ddy;
            #pragma unroll
            for (int q = 0; q < 4; q++) {
                float cx = (float)(jlo + q) * 8.0f + 3.5f;
                float ddx = wx - cx;
                float dv = ddy2 + ddx * ddx;
                int id = (ilo + a) * WC + (jlo + q);
                if (dv < bd3) {             // strict: lower index wins ties
                    bd3 = dv; id3 = id;
                    if (bd3 < bd2) { float tf=bd2; bd2=bd3; bd3=tf; int ti=id2; id2=id3; id3=ti; }
                    if (bd2 < bd1) { float tf=bd1; bd1=bd2; bd2=tf; int ti=id1; id1=id2; id2=ti; }
                    if (bd1 < bd0) { float tf=bd0; bd0=bd1; bd1=tf; int ti=id0; id0=id1; id1=ti; }
                }
            }
        }
        int base = ilo * WC + jlo;
        int mask = 0;
        {
            int d, ri, rj;
            d = id0 - base; ri = d / WC; rj = d - ri * WC; mask |= 1 << (ri*4+rj);
            d = id1 - base; ri = d / WC; rj = d - ri * WC; mask |= 1 << (ri*4+rj);
            d = id2 - base; ri = d / WC; rj = d - ri * WC; mask |= 1 << (ri*4+rj);
            d = id3 - base; ri = d / WC; rj = d - ri * WC; mask |= 1 << (ri*4+rj);
        }
        neighpk[idx] = mask | (ilo << 16) | (jlo << 24);
        negbits[idx] = 0x7F800000u;      // +inf
    }
}

// ============ k_negmin: LDS-staged MFMA GEMM, 3-buffer counted-vmcnt pipeline ============
// R6 body with stage-distance-2: the in-loop barrier never drains vmcnt to 0, so the
// stage issued 2 iterations ago is long complete when consumed. Bias staged via a
// width-4 GLL so COMP contains zero VMEM ops (vmcnt arithmetic: 3 ops per STAGE).
// key = s + {16 vis, 8 invis}; neighbor cols: key -= 8; argmax(key)==argmin(desc_sim).

#define GLL16(gp, lp) __builtin_amdgcn_global_load_lds(                      \
    (const __attribute__((address_space(1))) unsigned int*)(gp),             \
    (__attribute__((address_space(3))) unsigned int*)(lp), 16, 0, 0)
#define GLL4(gp, lp) __builtin_amdgcn_global_load_lds(                       \
    (const __attribute__((address_space(1))) unsigned int*)(gp),             \
    (__attribute__((address_space(3))) unsigned int*)(lp), 4, 0, 0)

#define MFMA16(A, B, C) __builtin_amdgcn_mfma_f32_16x16x32_bf16((A), (B), (C), 0, 0, 0)

__global__ __launch_bounds__(256) void k_negmin(
    const unsigned short* __restrict__ d1bf, const unsigned short* __restrict__ d2bf,
    const float* __restrict__ biasf, const int* __restrict__ neighpk,
    unsigned int* __restrict__ negbits)
{
    __shared__ unsigned short Bsm[3][4096];   // 3 x 8 KB tiles
    __shared__ float Bias[3][64];

    int bid = blockIdx.x;                 // BB * 150 * 8 = 2400
    int b   = bid / (150 * TGN);
    int rem = bid % (150 * TGN);
    int rb  = rem >> 3;                   // row-block 0..149
    int tg  = rem & 7;                    // col-group 0..7
    int tid = threadIdx.x;
    int w   = tid >> 6;
    int lane = tid & 63;
    int l15 = lane & 15, lg = lane >> 4;
    int r0  = rb * 32;
    int wl  = w * 16 + l15;               // col within a 64-col tile
    int lg8 = lg * 8;
    int bNN = b * NN;

    const unsigned short* d1b = d1bf + (size_t)bNN * CC;
    const unsigned short* d2b = d2bf + (size_t)bNN * CC;

    short8v afr00 = *(const short8v*)(d1b + (size_t)(r0 + l15) * CC + lg8);
    short8v afr01 = *(const short8v*)(d1b + (size_t)(r0 + l15) * CC + 32 + lg8);
    short8v afr10 = *(const short8v*)(d1b + (size_t)(r0 + 16 + l15) * CC + lg8);
    short8v afr11 = *(const short8v*)(d1b + (size_t)(r0 + 16 + l15) * CC + 32 + lg8);

    int pk[8];
    int lmin = 0x7FFFFFFF, lmax = -1;
    #pragma unroll
    for (int s_ = 0; s_ < 8; s_++) {
        int row = r0 + (s_ >> 2) * 16 + lg * 4 + (s_ & 3);
        int p = neighpk[bNN + row];
        pk[s_] = p;
        int ilo = (p >> 16) & 0xFF, jlo = (p >> 24) & 0xFF;
        int idm = ilo * WC + jlo;
        lmin = min(lmin, idm);
        lmax = max(lmax, idm + 3 * WC + 3);
    }
    #pragma unroll
    for (int off = 1; off < 64; off <<= 1) {
        lmin = min(lmin, __shfl_xor(lmin, off));
        lmax = max(lmax, __shfl_xor(lmax, off));
    }

    float m[8];
    #pragma unroll
    for (int i = 0; i < 8; i++) m[i] = -BIGF;

    // staging lane constants: LDS granules o0/o1, pre-swizzled global granules s0/s1
    int o0 = w * 64 + lane;
    int o1 = o0 + 256;
    int s0 = (o0 & ~7) | ((o0 ^ (o0 >> 3)) & 7);
    int s1 = (o1 & ~7) | ((o1 ^ (o1 >> 3)) & 7);

    int nt = (NTILES - tg + 7) >> 3;      // 10 for tg<3, else 9

#define STAGE(T, S) do {                                                     \
    const unsigned short* tbp_ = d2b + (size_t)((T) * 64) * CC;              \
    GLL16(tbp_ + s0 * 8, &Bsm[S][w * 512]);                                  \
    GLL16(tbp_ + s1 * 8, &Bsm[S][2048 + w * 512]);                           \
    GLL4(biasf + bNN + (T) * 64 + lane, &Bias[S][0]);                        \
} while (0)

#define COMP(T, S) do {                                                      \
    const unsigned short* lb_ = &Bsm[S][0];                                  \
    short8v b0_ = *(const short8v*)(lb_ + (size_t)wl * 64 +                  \
                                    (size_t)((lg ^ wl) & 7) * 8);            \
    short8v b1_ = *(const short8v*)(lb_ + (size_t)wl * 64 +                  \
                                    (size_t)(((4 + lg) ^ wl) & 7) * 8);      \
    float bi_ = Bias[S][wl];                                                 \
    f32x4 a0_ = {bi_, bi_, bi_, bi_};                                        \
    f32x4 a1_ = a0_;                                                         \
    a0_ = MFMA16(afr00, b0_, a0_);                                           \
    a0_ = MFMA16(afr01, b1_, a0_);                                           \
    a1_ = MFMA16(afr10, b0_, a1_);                                           \
    a1_ = MFMA16(afr11, b1_, a1_);                                           \
    int tb_ = (T) * 64;                                                      \
    if (tb_ + 63 < lmin || tb_ > lmax) {                                     \
        _Pragma("unroll")                                                    \
        for (int g_ = 0; g_ < 4; g_++) {                                     \
            m[g_]   = fmaxf(m[g_],   a0_[g_]);                               \
            m[4+g_] = fmaxf(m[4+g_], a1_[g_]);                               \
        }                                                                    \
    } else {                                                                 \
        int c_ = tb_ + wl;                                                   \
        int gi_ = c_ / WC; int gj_ = c_ - gi_ * WC;                          \
        _Pragma("unroll")                                                    \
        for (int s_ = 0; s_ < 8; s_++) {                                     \
            int p_ = pk[s_]; int msk_ = p_ & 0xFFFF;                         \
            unsigned ri_ = (unsigned)(gi_ - ((p_ >> 16) & 0xFF));            \
            unsigned rj_ = (unsigned)(gj_ - ((p_ >> 24) & 0xFF));            \
            unsigned bx_ = (ri_ < 4u && rj_ < 4u) ? (ri_ * 4u + rj_) : 16u;  \
            bool nb_ = ((msk_ >> bx_) & 1) != 0;                             \
            float sv_ = (s_ < 4) ? a0_[s_ & 3] : a1_[s_ & 3];                \
            float key_ = nb_ ? sv_ - 8.0f : sv_;                             \
            m[s_] = fmaxf(m[s_], key_);                                      \
        }                                                                    \
    }                                                                        \
} while (0)

    // prologue: stage tiles 0 and 1
    STAGE(tg, 0);
    STAGE(tg + 8, 1);

    // main loop: stage it+2, wait for stage it (newest 2 stages = 6 ops stay in
    // flight), barrier, compute, barrier (no drain -> pipeline persists)
    int it = 0;
    for (; it + 2 < nt; it++) {
        STAGE(tg + (it + 2) * 8, (it + 2) % 3);
        asm volatile("s_waitcnt vmcnt(6)\n\ts_barrier" ::: "memory");
        COMP(tg + it * 8, it % 3);
        asm volatile("s_barrier" ::: "memory");
    }
    // tail it = nt-2: only stage nt-1 outstanding (3 ops)
    asm volatile("s_waitcnt vmcnt(3)\n\ts_barrier" ::: "memory");
    COMP(tg + it * 8, it % 3);
    asm volatile("s_barrier" ::: "memory");
    it++;
    // tail it = nt-1: drain
    asm volatile("s_waitcnt vmcnt(0)\n\ts_barrier" ::: "memory");
    COMP(tg + it * 8, it % 3);

    // finalize: decode band -> penalty, sqrt, 16-lane min-reduce, atomicMin per row
    #pragma unroll
    for (int s_ = 0; s_ < 8; s_++) {
        float mv = m[s_];
        float pen, sdot;
        if (mv >= 12.0f)     { pen = 0.0f;  sdot = mv - 16.0f; }
        else if (mv >= 4.0f) { pen = 5.0f;  sdot = mv - 8.0f; }
        else                 { pen = 10.0f; sdot = mv; }
        float res = sqrtf(fmaxf(2.0f - 2.0f * sdot, EPSF)) + pen;
        #pragma unroll
        for (int off = 1; off < 16; off <<= 1)
            res = fminf(res, __shfl_xor(res, off));
        if (l15 == 0) {
            int row = r0 + (s_ >> 2) * 16 + lg * 4 + (s_ & 3);
            atomicMin(&negbits[bNN + row], __float_as_uint(res));
        }
    }
}

// ============ final loss (single block, separate kernel — cannot perturb k_negmin) ============
__global__ __launch_bounds__(1024) void k_final(
    const float* __restrict__ posim, const float* __restrict__ matchm,
    const unsigned int* __restrict__ negbits, float* __restrict__ out)
{
    __shared__ float sn[1024], sd[1024];
    int tid = threadIdx.x;
    float num = 0.0f, den = 0.0f;
    for (int i = tid; i < BB * NN; i += 1024) {
        float neg = __uint_as_float(negbits[i]);
        float l = fmaxf(posim[i] - neg + 1.0f, 0.0f);
        float mm = matchm[i];
        num += l * l * mm;
        den += mm;
    }
    sn[tid] = num; sd[tid] = den;
    __syncthreads();
    for (int s = 512; s > 0; s >>= 1) {
        if (tid < s) { sn[tid] += sn[tid + s]; sd[tid] += sd[tid + s]; }
        __syncthreads();
    }
    if (tid == 0) out[0] = sn[0] / sd[0];
}

extern "C" void kernel_launch(void* const* d_in, const int* in_sizes, int n_in,
                              void* d_out, int out_size, void* d_ws, size_t ws_size,
                              hipStream_t stream)
{
    const float* desc1  = (const float*)d_in[2];
    const float* desc2  = (const float*)d_in[3];
    const float* homo12 = (const float*)d_in[4];
    const float* homo21 = (const float*)d_in[5];
    float* out = (float*)d_out;

    float*        biasf   = (float*)d_ws;                      // 9600
    float*        posim   = biasf + BB * NN;                   // 9600
    float*        matchm  = posim + BB * NN;                   // 9600
    int*          neighpk = (int*)(matchm + BB * NN);          // 9600
    unsigned int* negbits = (unsigned int*)(neighpk + BB * NN);// 9600
    unsigned short* d1bf  = (unsigned short*)(negbits + BB * NN);
    unsigned short* d2bf  = d1bf + (size_t)BB * NN * CC;

    int nb_pre = 2 * BB * NTILES + 2 * BB * NTILES * 4;        // 300 cvt + 2400 percell
    k_pre<<<nb_pre, 256, 0, stream>>>(desc1, desc2, homo12, homo21,
                                      d1bf, d2bf, posim, matchm, biasf, neighpk, negbits);
    k_negmin<<<BB * 150 * TGN, 256, 0, stream>>>(d1bf, d2bf, biasf, neighpk, negbits);
    k_final<<<1, 1024, 0, stream>>>(posim, matchm, negbits, out);
}

// Round 12
// 43.913 us; speedup vs baseline: 1.2409x; 1.2409x over previous
//
#include <hip/hip_runtime.h>
#include <math.h>

#define GS 8
#define HC 60
#define WC 80
#define NN 4800      // HC*WC
#define CC 64
#define BB 2
#define HIMG 480
#define WIMG 640
#define EPSF 1e-8f
#define NTILES 75    // 4800 / 64
#define TGN 8        // column-split groups
#define BIGF 1e30f

typedef __attribute__((ext_vector_type(8))) short short8v;  // 8 bf16 = 4 VGPR
typedef __attribute__((ext_vector_type(4))) float f32x4;

__device__ __forceinline__ unsigned short f2bf(float f) {
    unsigned u = __float_as_uint(f);
    u += 0x7FFFu + ((u >> 16) & 1u);      // RNE
    return (unsigned short)(u >> 16);
}

// ============ k_pre: cvt (blocks 0..299) | per-cell wave prep (blocks 300..2699) ============
__global__ __launch_bounds__(256) void k_pre(
    const float* __restrict__ desc1, const float* __restrict__ desc2,
    const float* __restrict__ homo12, const float* __restrict__ homo21,
    unsigned short* __restrict__ d1bf, unsigned short* __restrict__ d2bf,
    float* __restrict__ posim, float* __restrict__ matchm,
    float* __restrict__ biasf, int* __restrict__ neighpk,
    unsigned int* __restrict__ negbits)
{
    __shared__ unsigned short tile[CC][65];
    int bid = blockIdx.x;
    int tid = threadIdx.x;

    if (bid < 2 * BB * NTILES) {
        // ---- convert fp32 [b][ch][cell] -> bf16 [b][cell][ch] ----
        int arr = bid / (BB * NTILES);
        int rem = bid % (BB * NTILES);
        int b = rem / NTILES;
        int t = rem % NTILES;
        int c0 = t * 64;
        const float* in = arr ? desc2 : desc1;
        unsigned short* out = arr ? d2bf : d1bf;
        int w = tid >> 6, l = tid & 63;
        #pragma unroll
        for (int k = 0; k < 16; k++) {
            int ch = k * 4 + w;
            tile[ch][l] = f2bf(in[((size_t)(b * CC + ch)) * NN + c0 + l]);
        }
        __syncthreads();
        #pragma unroll
        for (int k = 0; k < 16; k++) {
            int cell = k * 4 + w;
            out[((size_t)b * NN + c0 + cell) * CC + l] = tile[l][cell];
        }
        return;
    }

    // ---- per-cell: one wave per cell ----
    int sub = bid - 2 * BB * NTILES;      // 0..2399
    int wv = tid >> 6, lane = tid & 63;
    int idx = sub * 4 + wv;               // 0..9599
    int b = idx / NN, r = idx - b * NN;
    int ci = r / WC, cj = r - ci * WC;

    // visibility: lane = pixel (di,dj) of the 8x8 cell
    int allv;
    {
        const float* h = homo21 + b * 9;
        int di = lane >> 3, dj = lane & 7;
        float y = (float)(ci * 8 + di);
        float x = (float)(cj * 8 + dj);
        float qx = h[0]*x + h[1]*y + h[2];
        float qy = h[3]*x + h[4]*y + h[5];
        float qw = h[6]*x + h[7]*y + h[8];
        float px = qx / (qw + EPSF);
        float py = qy / (qw + EPSF);
        float y0 = floorf(py), x0 = floorf(px);
        float ty = py - y0,   tx = px - x0;
        float fyv = ((y0 >= 0.0f && y0 <= (float)(HIMG-1)) ? (1.0f-ty) : 0.0f)
                  + ((y0+1.0f >= 0.0f && y0+1.0f <= (float)(HIMG-1)) ? ty : 0.0f);
        float fxv = ((x0 >= 0.0f && x0 <= (float)(WIMG-1)) ? (1.0f-tx) : 0.0f)
                  + ((x0+1.0f >= 0.0f && x0+1.0f <= (float)(WIMG-1)) ? tx : 0.0f);
        int ok = (fyv > 0.0f && fxv > 0.0f) ? 1 : 0;
        allv = __all(ok);
    }

    // warp + bilinear setup (all lanes redundantly, uniform)
    const float* h = homo12 + b * 9;
    float xx = cj * 8.0f + 3.5f;
    float yy = ci * 8.0f + 3.5f;
    float qx = h[0]*xx + h[1]*yy + h[2];
    float qy = h[3]*xx + h[4]*yy + h[5];
    float qw = h[6]*xx + h[7]*yy + h[8];
    float wx = qx / (qw + EPSF);
    float wy = qy / (qw + EPSF);
    float dy = (wy - 4.0f + 0.5f) / 8.0f;
    float dx = (wx - 4.0f + 0.5f) / 8.0f;

    float y0f = floorf(dy), x0f = floorf(dx);
    float fy = dy - y0f, fx = dx - x0f;
    float y1f = y0f + 1.0f, x1f = x0f + 1.0f;
    bool v0y = (y0f >= 0.0f && y0f <= (float)(HC-1));
    bool v1y = (y1f >= 0.0f && y1f <= (float)(HC-1));
    bool v0x = (x0f >= 0.0f && x0f <= (float)(WC-1));
    bool v1x = (x1f >= 0.0f && x1f <= (float)(WC-1));
    float w00 = (1.0f-fy)*(1.0f-fx); if (!(v0y && v0x)) w00 = 0.0f;
    float w01 = (1.0f-fy)*fx;        if (!(v0y && v1x)) w01 = 0.0f;
    float w10 = fy*(1.0f-fx);        if (!(v1y && v0x)) w10 = 0.0f;
    float w11 = fy*fx;               if (!(v1y && v1x)) w11 = 0.0f;
    int yc0 = (int)fminf(fmaxf(y0f, 0.0f), (float)(HC-1));
    int yc1 = (int)fminf(fmaxf(y1f, 0.0f), (float)(HC-1));
    int xc0 = (int)fminf(fmaxf(x0f, 0.0f), (float)(WC-1));
    int xc1 = (int)fminf(fmaxf(x1f, 0.0f), (float)(WC-1));
    int o00 = yc0*WC + xc0, o01 = yc0*WC + xc1;
    int o10 = yc1*WC + xc0, o11 = yc1*WC + xc1;

    // lane = channel
    int ch = lane;
    const float* d2b = desc2 + (size_t)b * CC * NN;
    const float* p = d2b + ch * NN;
    float wvl = w00*p[o00] + w01*p[o01] + w10*p[o10] + w11*p[o11];
    float s2 = wvl * wvl;
    float sd = desc1[((size_t)(b * CC + ch)) * NN + r] * wvl;
    #pragma unroll
    for (int off = 1; off < 64; off <<= 1) {
        s2 += __shfl_xor(s2, off);
        sd += __shfl_xor(sd, off);
    }

    if (lane == 0) {
        biasf[idx] = allv ? 16.0f : 8.0f;
        matchm[idx] = (wy >= 0.0f && wy <= (float)(HIMG-1) &&
                       wx >= 0.0f && wx <= (float)(WIMG-1)) ? 1.0f : 0.0f;
        float dot = sd / (sqrtf(s2) + EPSF);
        posim[idx] = sqrtf(fmaxf(2.0f - 2.0f*dot, EPSF));

        // top-4 nearest grid centers -> packed bbox mask
        int i0 = (int)floorf(dy);
        int j0 = (int)floorf(dx);
        int ilo = i0 - 1; if (ilo < 0) ilo = 0; if (ilo > HC-4) ilo = HC-4;
        int jlo = j0 - 1; if (jlo < 0) jlo = 0; if (jlo > WC-4) jlo = WC-4;
        float bd0=3e38f, bd1=3e38f, bd2=3e38f, bd3=3e38f;
        int   id0=0,     id1=0,     id2=0,     id3=0;
        #pragma unroll
        for (int a = 0; a < 4; a++) {
            float cy = (float)(ilo + a) * 8.0f + 3.5f;
            float ddy = wy - cy;
            float ddy2 = ddy * ddy;
            #pragma unroll
            for (int q = 0; q < 4; q++) {
                float cx = (float)(jlo + q) * 8.0f + 3.5f;
                float ddx = wx - cx;
                float dv = ddy2 + ddx * ddx;
                int id = (ilo + a) * WC + (jlo + q);
                if (dv < bd3) {             // strict: lower index wins ties
                    bd3 = dv; id3 = id;
                    if (bd3 < bd2) { float tf=bd2; bd2=bd3; bd3=tf; int ti=id2; id2=id3; id3=ti; }
                    if (bd2 < bd1) { float tf=bd1; bd1=bd2; bd2=tf; int ti=id1; id1=id2; id2=ti; }
                    if (bd1 < bd0) { float tf=bd0; bd0=bd1; bd1=tf; int ti=id0; id0=id1; id1=ti; }
                }
            }
        }
        int base = ilo * WC + jlo;
        int mask = 0;
        {
            int d, ri, rj;
            d = id0 - base; ri = d / WC; rj = d - ri * WC; mask |= 1 << (ri*4+rj);
            d = id1 - base; ri = d / WC; rj = d - ri * WC; mask |= 1 << (ri*4+rj);
            d = id2 - base; ri = d / WC; rj = d - ri * WC; mask |= 1 << (ri*4+rj);
            d = id3 - base; ri = d / WC; rj = d - ri * WC; mask |= 1 << (ri*4+rj);
        }
        neighpk[idx] = mask | (ilo << 16) | (jlo << 24);
        negbits[idx] = 0x7F800000u;      // +inf
    }
}

// ============ k_negmin: LDS-staged MFMA GEMM + single-key max (R6-exact) ============
// B staged via global_load_lds (linear LDS dest, pre-swizzled global src granules).
// bias folded into MFMA acc init: key = s + {16 vis, 8 invis}; neighbor cols: key -= 8;
// argmax(key) == argmin(desc_sim) exactly (bands 5-separated, sqrt(2-2s) in [0,2]).
// NOTE: this body sits just under the compiler's regalloc cliff — any added live
// state or hand-scheduling pushed it into a 64-VGPR spill regime (R5/R7/R9/R11).
// Do not modify.

#define GLL(gp, lp) __builtin_amdgcn_global_load_lds(                        \
    (const __attribute__((address_space(1))) unsigned int*)(gp),             \
    (__attribute__((address_space(3))) unsigned int*)(lp), 16, 0, 0)

#define MFMA16(A, B, C) __builtin_amdgcn_mfma_f32_16x16x32_bf16((A), (B), (C), 0, 0, 0)

__global__ __launch_bounds__(256) void k_negmin(
    const unsigned short* __restrict__ d1bf, const unsigned short* __restrict__ d2bf,
    const float* __restrict__ biasf, const int* __restrict__ neighpk,
    unsigned int* __restrict__ negbits)
{
    __shared__ unsigned short Bsm[2][4096];   // 2 x 8 KB tiles

    int bid = blockIdx.x;                 // BB * 150 * 8 = 2400
    int b   = bid / (150 * TGN);
    int rem = bid % (150 * TGN);
    int rb  = rem >> 3;                   // row-block 0..149
    int tg  = rem & 7;                    // col-group 0..7
    int tid = threadIdx.x;
    int w   = tid >> 6;
    int lane = tid & 63;
    int l15 = lane & 15, lg = lane >> 4;
    int r0  = rb * 32;
    int wl  = w * 16 + l15;               // col within a 64-col tile
    int lg8 = lg * 8;
    int bNN = b * NN;

    const unsigned short* d1b = d1bf + (size_t)bNN * CC;
    const unsigned short* d2b = d2bf + (size_t)bNN * CC;

    short8v afr00 = *(const short8v*)(d1b + (size_t)(r0 + l15) * CC + lg8);
    short8v afr01 = *(const short8v*)(d1b + (size_t)(r0 + l15) * CC + 32 + lg8);
    short8v afr10 = *(const short8v*)(d1b + (size_t)(r0 + 16 + l15) * CC + lg8);
    short8v afr11 = *(const short8v*)(d1b + (size_t)(r0 + 16 + l15) * CC + 32 + lg8);

    int pk[8];
    int lmin = 0x7FFFFFFF, lmax = -1;
    #pragma unroll
    for (int s_ = 0; s_ < 8; s_++) {
        int row = r0 + (s_ >> 2) * 16 + lg * 4 + (s_ & 3);
        int p = neighpk[bNN + row];
        pk[s_] = p;
        int ilo = (p >> 16) & 0xFF, jlo = (p >> 24) & 0xFF;
        int idm = ilo * WC + jlo;
        lmin = min(lmin, idm);
        lmax = max(lmax, idm + 3 * WC + 3);
    }
    #pragma unroll
    for (int off = 1; off < 64; off <<= 1) {
        lmin = min(lmin, __shfl_xor(lmin, off));
        lmax = max(lmax, __shfl_xor(lmax, off));
    }

    float m[8];
    #pragma unroll
    for (int i = 0; i < 8; i++) m[i] = -BIGF;

    // staging lane constants: LDS granules o0/o1, pre-swizzled global granules s0/s1
    int o0 = w * 64 + lane;
    int o1 = o0 + 256;
    int s0 = (o0 & ~7) | ((o0 ^ (o0 >> 3)) & 7);
    int s1 = (o1 & ~7) | ((o1 ^ (o1 >> 3)) & 7);

    int nt = (NTILES - tg + 7) >> 3;      // 10 for tg<3, else 9

    // prologue: stage first tile
    {
        const unsigned short* tb0 = d2b + (size_t)(tg * 64) * CC;
        GLL(tb0 + s0 * 8, &Bsm[0][w * 512]);
        GLL(tb0 + s1 * 8, &Bsm[0][2048 + w * 512]);
    }
    float bias = biasf[bNN + tg * 64 + wl];
    __syncthreads();

    int buf = 0;
    for (int it = 0; it < nt; it++) {
        int t = tg + it * 8;

        // issue next tile's stage early (hides under MFMA+epilogue; barrier drains it)
        float bias_n = 0.0f;
        if (it + 1 < nt) {
            const unsigned short* tbn = d2b + (size_t)((t + 8) * 64) * CC;
            GLL(tbn + s0 * 8, &Bsm[buf ^ 1][w * 512]);
            GLL(tbn + s1 * 8, &Bsm[buf ^ 1][2048 + w * 512]);
            bias_n = biasf[bNN + (t + 8) * 64 + wl];
        }

        // B frags from LDS (swizzled granule read)
        const unsigned short* lb = &Bsm[buf][0];
        short8v b0 = *(const short8v*)(lb + (size_t)wl * 64 + (size_t)((lg ^ wl) & 7) * 8);
        short8v b1 = *(const short8v*)(lb + (size_t)wl * 64 + (size_t)(((4 + lg) ^ wl) & 7) * 8);

        f32x4 a0 = {bias, bias, bias, bias};
        f32x4 a1 = a0;
        a0 = MFMA16(afr00, b0, a0);
        a0 = MFMA16(afr01, b1, a0);
        a1 = MFMA16(afr10, b0, a1);
        a1 = MFMA16(afr11, b1, a1);

        int tb = t * 64;
        if (tb + 63 < lmin || tb > lmax) {
            #pragma unroll
            for (int g_ = 0; g_ < 4; g_++) {
                m[g_]   = fmaxf(m[g_],   a0[g_]);
                m[4+g_] = fmaxf(m[4+g_], a1[g_]);
            }
        } else {
            int c_ = tb + wl;
            int gi_ = c_ / WC; int gj_ = c_ - gi_ * WC;
            #pragma unroll
            for (int s_ = 0; s_ < 8; s_++) {
                int p_ = pk[s_]; int msk_ = p_ & 0xFFFF;
                unsigned ri_ = (unsigned)(gi_ - ((p_ >> 16) & 0xFF));
                unsigned rj_ = (unsigned)(gj_ - ((p_ >> 24) & 0xFF));
                unsigned bx_ = (ri_ < 4u && rj_ < 4u) ? (ri_ * 4u + rj_) : 16u;
                bool nb_ = ((msk_ >> bx_) & 1) != 0;
                float sv_ = (s_ < 4) ? a0[s_ & 3] : a1[s_ & 3];
                float key_ = nb_ ? sv_ - 8.0f : sv_;
                m[s_] = fmaxf(m[s_], key_);
            }
        }

        bias = bias_n;
        buf ^= 1;
        __syncthreads();   // next tile staged + all reads of old buf done
    }

    // finalize: decode band -> penalty, sqrt, 16-lane min-reduce, atomicMin per row
    #pragma unroll
    for (int s_ = 0; s_ < 8; s_++) {
        float mv = m[s_];
        float pen, sdot;
        if (mv >= 12.0f)     { pen = 0.0f;  sdot = mv - 16.0f; }
        else if (mv >= 4.0f) { pen = 5.0f;  sdot = mv - 8.0f; }
        else                 { pen = 10.0f; sdot = mv; }
        float res = sqrtf(fmaxf(2.0f - 2.0f * sdot, EPSF)) + pen;
        #pragma unroll
        for (int off = 1; off < 16; off <<= 1)
            res = fminf(res, __shfl_xor(res, off));
        if (l15 == 0) {
            int row = r0 + (s_ >> 2) * 16 + lg * 4 + (s_ & 3);
            atomicMin(&negbits[bNN + row], __float_as_uint(res));
        }
    }
}

// ============ per-row loss partials (38 blocks) + final sum ============
__global__ void k_loss(const float* __restrict__ posim, const float* __restrict__ matchm,
                       const unsigned int* __restrict__ negbits, float* __restrict__ bpart)
{
    __shared__ float sn[256], sdn[256];
    int tid = threadIdx.x;
    int idx = blockIdx.x * 256 + tid;
    float num = 0.0f, den = 0.0f;
    if (idx < BB * NN) {
        float neg = __uint_as_float(negbits[idx]);
        float l = fmaxf(posim[idx] - neg + 1.0f, 0.0f);
        float mm = matchm[idx];
        num = l * l * mm;
        den = mm;
    }
    sn[tid] = num; sdn[tid] = den;
    __syncthreads();
    for (int st = 128; st > 0; st >>= 1) {
        if (tid < st) { sn[tid] += sn[tid + st]; sdn[tid] += sdn[tid + st]; }
        __syncthreads();
    }
    if (tid == 0) { bpart[blockIdx.x * 2] = sn[0]; bpart[blockIdx.x * 2 + 1] = sdn[0]; }
}

__global__ void k_sum(const float* __restrict__ bpart, int nb, float* __restrict__ out)
{
    int t = threadIdx.x;
    float num = 0.0f, den = 0.0f;
    if (t < nb) { num = bpart[t * 2]; den = bpart[t * 2 + 1]; }
    #pragma unroll
    for (int off = 1; off < 64; off <<= 1) {
        num += __shfl_xor(num, off);
        den += __shfl_xor(den, off);
    }
    if (t == 0) out[0] = num / den;
}

extern "C" void kernel_launch(void* const* d_in, const int* in_sizes, int n_in,
                              void* d_out, int out_size, void* d_ws, size_t ws_size,
                              hipStream_t stream)
{
    const float* desc1  = (const float*)d_in[2];
    const float* desc2  = (const float*)d_in[3];
    const float* homo12 = (const float*)d_in[4];
    const float* homo21 = (const float*)d_in[5];
    float* out = (float*)d_out;

    float*        biasf   = (float*)d_ws;                      // 9600
    float*        posim   = biasf + BB * NN;                   // 9600
    float*        matchm  = posim + BB * NN;                   // 9600
    int*          neighpk = (int*)(matchm + BB * NN);          // 9600
    unsigned int* negbits = (unsigned int*)(neighpk + BB * NN);// 9600
    float*        bpart   = (float*)(negbits + BB * NN);       // 128
    unsigned short* d1bf  = (unsigned short*)(bpart + 128);
    unsigned short* d2bf  = d1bf + (size_t)BB * NN * CC;

    int nb = (BB * NN + 255) / 256;                            // 38
    int nb_pre = 2 * BB * NTILES + 2 * BB * NTILES * 4;        // 300 cvt + 2400 percell
    k_pre<<<nb_pre, 256, 0, stream>>>(desc1, desc2, homo12, homo21,
                                      d1bf, d2bf, posim, matchm, biasf, neighpk, negbits);
    k_negmin<<<BB * 150 * TGN, 256, 0, stream>>>(d1bf, d2bf, biasf, neighpk, negbits);
    k_loss<<<nb, 256, 0, stream>>>(posim, matchm, negbits, bpart);
    k_sum<<<1, 64, 0, stream>>>(bpart, nb, out);
}

// Round 13
// 43.142 us; speedup vs baseline: 1.2631x; 1.0179x over previous
//
#include <hip/hip_runtime.h>
#include <math.h>

#define GS 8
#define HC 60
#define WC 80
#define NN 4800      // HC*WC
#define CC 64
#define BB 2
#define HIMG 480
#define WIMG 640
#define EPSF 1e-8f
#define NCT 150      // 32-col tiles (4800 / 32)
#define TGN 16       // column-split groups
#define BIGF 1e30f

typedef __attribute__((ext_vector_type(8))) short short8v;  // 8 bf16 = 4 VGPR
typedef __attribute__((ext_vector_type(4))) float f32x4;

__device__ __forceinline__ unsigned short f2bf(float f) {
    unsigned u = __float_as_uint(f);
    u += 0x7FFFu + ((u >> 16) & 1u);      // RNE
    return (unsigned short)(u >> 16);
}

// ============ k_pre: cvt (blocks 0..299) | per-cell wave prep (blocks 300..2699) ============
__global__ __launch_bounds__(256) void k_pre(
    const float* __restrict__ desc1, const float* __restrict__ desc2,
    const float* __restrict__ homo12, const float* __restrict__ homo21,
    unsigned short* __restrict__ d1bf, unsigned short* __restrict__ d2bf,
    float* __restrict__ posim, float* __restrict__ matchm,
    float* __restrict__ biasf, int* __restrict__ neighpk,
    unsigned int* __restrict__ negbits)
{
    __shared__ unsigned short tile[CC][65];
    int bid = blockIdx.x;
    int tid = threadIdx.x;

    if (bid < 2 * BB * 75) {
        // ---- convert fp32 [b][ch][cell] -> bf16 [b][cell][ch] ----
        int arr = bid / (BB * 75);
        int rem = bid % (BB * 75);
        int b = rem / 75;
        int t = rem % 75;
        int c0 = t * 64;
        const float* in = arr ? desc2 : desc1;
        unsigned short* out = arr ? d2bf : d1bf;
        int w = tid >> 6, l = tid & 63;
        #pragma unroll
        for (int k = 0; k < 16; k++) {
            int ch = k * 4 + w;
            tile[ch][l] = f2bf(in[((size_t)(b * CC + ch)) * NN + c0 + l]);
        }
        __syncthreads();
        #pragma unroll
        for (int k = 0; k < 16; k++) {
            int cell = k * 4 + w;
            out[((size_t)b * NN + c0 + cell) * CC + l] = tile[l][cell];
        }
        return;
    }

    // ---- per-cell: one wave per cell ----
    int sub = bid - 2 * BB * 75;          // 0..2399
    int wv = tid >> 6, lane = tid & 63;
    int idx = sub * 4 + wv;               // 0..9599
    int b = idx / NN, r = idx - b * NN;
    int ci = r / WC, cj = r - ci * WC;

    // visibility: lane = pixel (di,dj) of the 8x8 cell
    int allv;
    {
        const float* h = homo21 + b * 9;
        int di = lane >> 3, dj = lane & 7;
        float y = (float)(ci * 8 + di);
        float x = (float)(cj * 8 + dj);
        float qx = h[0]*x + h[1]*y + h[2];
        float qy = h[3]*x + h[4]*y + h[5];
        float qw = h[6]*x + h[7]*y + h[8];
        float px = qx / (qw + EPSF);
        float py = qy / (qw + EPSF);
        float y0 = floorf(py), x0 = floorf(px);
        float ty = py - y0,   tx = px - x0;
        float fyv = ((y0 >= 0.0f && y0 <= (float)(HIMG-1)) ? (1.0f-ty) : 0.0f)
                  + ((y0+1.0f >= 0.0f && y0+1.0f <= (float)(HIMG-1)) ? ty : 0.0f);
        float fxv = ((x0 >= 0.0f && x0 <= (float)(WIMG-1)) ? (1.0f-tx) : 0.0f)
                  + ((x0+1.0f >= 0.0f && x0+1.0f <= (float)(WIMG-1)) ? tx : 0.0f);
        int ok = (fyv > 0.0f && fxv > 0.0f) ? 1 : 0;
        allv = __all(ok);
    }

    // warp + bilinear setup (all lanes redundantly, uniform)
    const float* h = homo12 + b * 9;
    float xx = cj * 8.0f + 3.5f;
    float yy = ci * 8.0f + 3.5f;
    float qx = h[0]*xx + h[1]*yy + h[2];
    float qy = h[3]*xx + h[4]*yy + h[5];
    float qw = h[6]*xx + h[7]*yy + h[8];
    float wx = qx / (qw + EPSF);
    float wy = qy / (qw + EPSF);
    float dy = (wy - 4.0f + 0.5f) / 8.0f;
    float dx = (wx - 4.0f + 0.5f) / 8.0f;

    float y0f = floorf(dy), x0f = floorf(dx);
    float fy = dy - y0f, fx = dx - x0f;
    float y1f = y0f + 1.0f, x1f = x0f + 1.0f;
    bool v0y = (y0f >= 0.0f && y0f <= (float)(HC-1));
    bool v1y = (y1f >= 0.0f && y1f <= (float)(HC-1));
    bool v0x = (x0f >= 0.0f && x0f <= (float)(WC-1));
    bool v1x = (x1f >= 0.0f && x1f <= (float)(WC-1));
    float w00 = (1.0f-fy)*(1.0f-fx); if (!(v0y && v0x)) w00 = 0.0f;
    float w01 = (1.0f-fy)*fx;        if (!(v0y && v1x)) w01 = 0.0f;
    float w10 = fy*(1.0f-fx);        if (!(v1y && v0x)) w10 = 0.0f;
    float w11 = fy*fx;               if (!(v1y && v1x)) w11 = 0.0f;
    int yc0 = (int)fminf(fmaxf(y0f, 0.0f), (float)(HC-1));
    int yc1 = (int)fminf(fmaxf(y1f, 0.0f), (float)(HC-1));
    int xc0 = (int)fminf(fmaxf(x0f, 0.0f), (float)(WC-1));
    int xc1 = (int)fminf(fmaxf(x1f, 0.0f), (float)(WC-1));
    int o00 = yc0*WC + xc0, o01 = yc0*WC + xc1;
    int o10 = yc1*WC + xc0, o11 = yc1*WC + xc1;

    // lane = channel
    int ch = lane;
    const float* d2b = desc2 + (size_t)b * CC * NN;
    const float* p = d2b + ch * NN;
    float wvl = w00*p[o00] + w01*p[o01] + w10*p[o10] + w11*p[o11];
    float s2 = wvl * wvl;
    float sd = desc1[((size_t)(b * CC + ch)) * NN + r] * wvl;
    #pragma unroll
    for (int off = 1; off < 64; off <<= 1) {
        s2 += __shfl_xor(s2, off);
        sd += __shfl_xor(sd, off);
    }

    if (lane == 0) {
        biasf[idx] = allv ? 16.0f : 8.0f;
        matchm[idx] = (wy >= 0.0f && wy <= (float)(HIMG-1) &&
                       wx >= 0.0f && wx <= (float)(WIMG-1)) ? 1.0f : 0.0f;
        float dot = sd / (sqrtf(s2) + EPSF);
        posim[idx] = sqrtf(fmaxf(2.0f - 2.0f*dot, EPSF));

        // top-4 nearest grid centers -> packed bbox mask
        int i0 = (int)floorf(dy);
        int j0 = (int)floorf(dx);
        int ilo = i0 - 1; if (ilo < 0) ilo = 0; if (ilo > HC-4) ilo = HC-4;
        int jlo = j0 - 1; if (jlo < 0) jlo = 0; if (jlo > WC-4) jlo = WC-4;
        float bd0=3e38f, bd1=3e38f, bd2=3e38f, bd3=3e38f;
        int   id0=0,     id1=0,     id2=0,     id3=0;
        #pragma unroll
        for (int a = 0; a < 4; a++) {
            float cy = (float)(ilo + a) * 8.0f + 3.5f;
            float ddy = wy - cy;
            float ddy2 = ddy * ddy;
            #pragma unroll
            for (int q = 0; q < 4; q++) {
                float cx = (float)(jlo + q) * 8.0f + 3.5f;
                float ddx = wx - cx;
                float dv = ddy2 + ddx * ddx;
                int id = (ilo + a) * WC + (jlo + q);
                if (dv < bd3) {             // strict: lower index wins ties
                    bd3 = dv; id3 = id;
                    if (bd3 < bd2) { float tf=bd2; bd2=bd3; bd3=tf; int ti=id2; id2=id3; id3=ti; }
                    if (bd2 < bd1) { float tf=bd1; bd1=bd2; bd2=tf; int ti=id1; id1=id2; id2=ti; }
                    if (bd1 < bd0) { float tf=bd0; bd0=bd1; bd1=tf; int ti=id0; id0=id1; id1=ti; }
                }
            }
        }
        int base = ilo * WC + jlo;
        int mask = 0;
        {
            int d, ri, rj;
            d = id0 - base; ri = d / WC; rj = d - ri * WC; mask |= 1 << (ri*4+rj);
            d = id1 - base; ri = d / WC; rj = d - ri * WC; mask |= 1 << (ri*4+rj);
            d = id2 - base; ri = d / WC; rj = d - ri * WC; mask |= 1 << (ri*4+rj);
            d = id3 - base; ri = d / WC; rj = d - ri * WC; mask |= 1 << (ri*4+rj);
        }
        neighpk[idx] = mask | (ilo << 16) | (jlo << 24);
        negbits[idx] = 0x7F800000u;      // +inf
    }
}

// ============ k_negmin: R6 body at 2-wave blocks / 32-col tiles ============
// Identical per-wave structure and register state to the R6 kernel; only the
// block geometry changes (128 threads, 4 KB tiles, TGN=16) -> 16 independent
// barrier domains per CU instead of 8, for finer mutual stall-hiding.

#define GLL(gp, lp) __builtin_amdgcn_global_load_lds(                        \
    (const __attribute__((address_space(1))) unsigned int*)(gp),             \
    (__attribute__((address_space(3))) unsigned int*)(lp), 16, 0, 0)

#define MFMA16(A, B, C) __builtin_amdgcn_mfma_f32_16x16x32_bf16((A), (B), (C), 0, 0, 0)

__global__ __launch_bounds__(128) void k_negmin(
    const unsigned short* __restrict__ d1bf, const unsigned short* __restrict__ d2bf,
    const float* __restrict__ biasf, const int* __restrict__ neighpk,
    unsigned int* __restrict__ negbits)
{
    __shared__ unsigned short Bsm[2][2048];   // 2 x 4 KB tiles (32 cols x 64 ch bf16)

    int bid = blockIdx.x;                 // BB * 150 * 16 = 4800
    int b   = bid / (150 * TGN);
    int rem = bid % (150 * TGN);
    int rb  = rem >> 4;                   // row-block 0..149
    int tg  = rem & 15;                   // col-group 0..15
    int tid = threadIdx.x;
    int w   = tid >> 6;                   // 0..1
    int lane = tid & 63;
    int l15 = lane & 15, lg = lane >> 4;
    int r0  = rb * 32;
    int wl  = w * 16 + l15;               // col within a 32-col tile
    int lg8 = lg * 8;
    int bNN = b * NN;

    const unsigned short* d1b = d1bf + (size_t)bNN * CC;
    const unsigned short* d2b = d2bf + (size_t)bNN * CC;

    short8v afr00 = *(const short8v*)(d1b + (size_t)(r0 + l15) * CC + lg8);
    short8v afr01 = *(const short8v*)(d1b + (size_t)(r0 + l15) * CC + 32 + lg8);
    short8v afr10 = *(const short8v*)(d1b + (size_t)(r0 + 16 + l15) * CC + lg8);
    short8v afr11 = *(const short8v*)(d1b + (size_t)(r0 + 16 + l15) * CC + 32 + lg8);

    int pk[8];
    int lmin = 0x7FFFFFFF, lmax = -1;
    #pragma unroll
    for (int s_ = 0; s_ < 8; s_++) {
        int row = r0 + (s_ >> 2) * 16 + lg * 4 + (s_ & 3);
        int p = neighpk[bNN + row];
        pk[s_] = p;
        int ilo = (p >> 16) & 0xFF, jlo = (p >> 24) & 0xFF;
        int idm = ilo * WC + jlo;
        lmin = min(lmin, idm);
        lmax = max(lmax, idm + 3 * WC + 3);
    }
    #pragma unroll
    for (int off = 1; off < 64; off <<= 1) {
        lmin = min(lmin, __shfl_xor(lmin, off));
        lmax = max(lmax, __shfl_xor(lmax, off));
    }

    float m[8];
    #pragma unroll
    for (int i = 0; i < 8; i++) m[i] = -BIGF;

    // staging lane constants: LDS granules o0/o1 (0..255), pre-swizzled global s0/s1
    int o0 = w * 64 + lane;               // 0..127
    int o1 = o0 + 128;                    // 128..255
    int s0 = (o0 & ~7) | ((o0 ^ (o0 >> 3)) & 7);
    int s1 = (o1 & ~7) | ((o1 ^ (o1 >> 3)) & 7);

    int nt = (NCT - tg + TGN - 1) >> 4;   // 10 for tg<6, else 9

    // prologue: stage first tile (granule g lives at short-offset g*8)
    {
        const unsigned short* tb0 = d2b + (size_t)(tg * 32) * CC;
        GLL(tb0 + s0 * 8, &Bsm[0][w * 512]);
        GLL(tb0 + s1 * 8, &Bsm[0][1024 + w * 512]);
    }
    float bias = biasf[bNN + tg * 32 + wl];
    __syncthreads();

    int buf = 0;
    for (int it = 0; it < nt; it++) {
        int t = tg + it * TGN;

        // issue next tile's stage early (hides under MFMA+epilogue; barrier drains it)
        float bias_n = 0.0f;
        if (it + 1 < nt) {
            const unsigned short* tbn = d2b + (size_t)((t + TGN) * 32) * CC;
            GLL(tbn + s0 * 8, &Bsm[buf ^ 1][w * 512]);
            GLL(tbn + s1 * 8, &Bsm[buf ^ 1][1024 + w * 512]);
            bias_n = biasf[bNN + (t + TGN) * 32 + wl];
        }

        // B frags from LDS (swizzled granule read; col stride = 8 granules)
        const unsigned short* lb = &Bsm[buf][0];
        short8v b0 = *(const short8v*)(lb + (size_t)wl * 64 + (size_t)((lg ^ wl) & 7) * 8);
        short8v b1 = *(const short8v*)(lb + (size_t)wl * 64 + (size_t)(((4 + lg) ^ wl) & 7) * 8);

        f32x4 a0 = {bias, bias, bias, bias};
        f32x4 a1 = a0;
        a0 = MFMA16(afr00, b0, a0);
        a0 = MFMA16(afr01, b1, a0);
        a1 = MFMA16(afr10, b0, a1);
        a1 = MFMA16(afr11, b1, a1);

        int tb = t * 32;
        if (tb + 31 < lmin || tb > lmax) {
            #pragma unroll
            for (int g_ = 0; g_ < 4; g_++) {
                m[g_]   = fmaxf(m[g_],   a0[g_]);
                m[4+g_] = fmaxf(m[4+g_], a1[g_]);
            }
        } else {
            int c_ = tb + wl;
            int gi_ = c_ / WC; int gj_ = c_ - gi_ * WC;
            #pragma unroll
            for (int s_ = 0; s_ < 8; s_++) {
                int p_ = pk[s_]; int msk_ = p_ & 0xFFFF;
                unsigned ri_ = (unsigned)(gi_ - ((p_ >> 16) & 0xFF));
                unsigned rj_ = (unsigned)(gj_ - ((p_ >> 24) & 0xFF));
                unsigned bx_ = (ri_ < 4u && rj_ < 4u) ? (ri_ * 4u + rj_) : 16u;
                bool nb_ = ((msk_ >> bx_) & 1) != 0;
                float sv_ = (s_ < 4) ? a0[s_ & 3] : a1[s_ & 3];
                float key_ = nb_ ? sv_ - 8.0f : sv_;
                m[s_] = fmaxf(m[s_], key_);
            }
        }

        bias = bias_n;
        buf ^= 1;
        __syncthreads();   // next tile staged + all reads of old buf done
    }

    // finalize: decode band -> penalty, sqrt, 16-lane min-reduce, atomicMin per row
    #pragma unroll
    for (int s_ = 0; s_ < 8; s_++) {
        float mv = m[s_];
        float pen, sdot;
        if (mv >= 12.0f)     { pen = 0.0f;  sdot = mv - 16.0f; }
        else if (mv >= 4.0f) { pen = 5.0f;  sdot = mv - 8.0f; }
        else                 { pen = 10.0f; sdot = mv; }
        float res = sqrtf(fmaxf(2.0f - 2.0f * sdot, EPSF)) + pen;
        #pragma unroll
        for (int off = 1; off < 16; off <<= 1)
            res = fminf(res, __shfl_xor(res, off));
        if (l15 == 0) {
            int row = r0 + (s_ >> 2) * 16 + lg * 4 + (s_ & 3);
            atomicMin(&negbits[bNN + row], __float_as_uint(res));
        }
    }
}

// ============ per-row loss partials (38 blocks) + final sum ============
__global__ void k_loss(const float* __restrict__ posim, const float* __restrict__ matchm,
                       const unsigned int* __restrict__ negbits, float* __restrict__ bpart)
{
    __shared__ float sn[256], sdn[256];
    int tid = threadIdx.x;
    int idx = blockIdx.x * 256 + tid;
    float num = 0.0f, den = 0.0f;
    if (idx < BB * NN) {
        float neg = __uint_as_float(negbits[idx]);
        float l = fmaxf(posim[idx] - neg + 1.0f, 0.0f);
        float mm = matchm[idx];
        num = l * l * mm;
        den = mm;
    }
    sn[tid] = num; sdn[tid] = den;
    __syncthreads();
    for (int st = 128; st > 0; st >>= 1) {
        if (tid < st) { sn[tid] += sn[tid + st]; sdn[tid] += sdn[tid + st]; }
        __syncthreads();
    }
    if (tid == 0) { bpart[blockIdx.x * 2] = sn[0]; bpart[blockIdx.x * 2 + 1] = sdn[0]; }
}

__global__ void k_sum(const float* __restrict__ bpart, int nb, float* __restrict__ out)
{
    int t = threadIdx.x;
    float num = 0.0f, den = 0.0f;
    if (t < nb) { num = bpart[t * 2]; den = bpart[t * 2 + 1]; }
    #pragma unroll
    for (int off = 1; off < 64; off <<= 1) {
        num += __shfl_xor(num, off);
        den += __shfl_xor(den, off);
    }
    if (t == 0) out[0] = num / den;
}

extern "C" void kernel_launch(void* const* d_in, const int* in_sizes, int n_in,
                              void* d_out, int out_size, void* d_ws, size_t ws_size,
                              hipStream_t stream)
{
    const float* desc1  = (const float*)d_in[2];
    const float* desc2  = (const float*)d_in[3];
    const float* homo12 = (const float*)d_in[4];
    const float* homo21 = (const float*)d_in[5];
    float* out = (float*)d_out;

    float*        biasf   = (float*)d_ws;                      // 9600
    float*        posim   = biasf + BB * NN;                   // 9600
    float*        matchm  = posim + BB * NN;                   // 9600
    int*          neighpk = (int*)(matchm + BB * NN);          // 9600
    unsigned int* negbits = (unsigned int*)(neighpk + BB * NN);// 9600
    float*        bpart   = (float*)(negbits + BB * NN);       // 128
    unsigned short* d1bf  = (unsigned short*)(bpart + 128);
    unsigned short* d2bf  = d1bf + (size_t)BB * NN * CC;

    int nb = (BB * NN + 255) / 256;                            // 38
    int nb_pre = 2 * BB * 75 + 2 * BB * 75 * 4;                // 300 cvt + 2400 percell
    k_pre<<<nb_pre, 256, 0, stream>>>(desc1, desc2, homo12, homo21,
                                      d1bf, d2bf, posim, matchm, biasf, neighpk, negbits);
    k_negmin<<<BB * 150 * TGN, 128, 0, stream>>>(d1bf, d2bf, biasf, neighpk, negbits);
    k_loss<<<nb, 256, 0, stream>>>(posim, matchm, negbits, bpart);
    k_sum<<<1, 64, 0, stream>>>(bpart, nb, out);
}

// Round 14
// 38.601 us; speedup vs baseline: 1.4117x; 1.1176x over previous
//
#include <hip/hip_runtime.h>
#include <math.h>

#define GS 8
#define HC 60
#define WC 80
#define NN 4800      // HC*WC
#define CC 64
#define BB 2
#define HIMG 480
#define WIMG 640
#define EPSF 1e-8f
#define NCT 300      // 16-col tiles (4800 / 16)
#define TGN 24       // column-split groups (grid = 2*150*24 = 7200 = 28.1/CU, one round)
#define BIGF 1e30f

typedef __attribute__((ext_vector_type(8))) short short8v;  // 8 bf16 = 4 VGPR
typedef __attribute__((ext_vector_type(4))) float f32x4;

__device__ __forceinline__ unsigned short f2bf(float f) {
    unsigned u = __float_as_uint(f);
    u += 0x7FFFu + ((u >> 16) & 1u);      // RNE
    return (unsigned short)(u >> 16);
}

// ============ k_pre: cvt (blocks 0..299) | per-cell wave prep (blocks 300..2699) ============
__global__ __launch_bounds__(256) void k_pre(
    const float* __restrict__ desc1, const float* __restrict__ desc2,
    const float* __restrict__ homo12, const float* __restrict__ homo21,
    unsigned short* __restrict__ d1bf, unsigned short* __restrict__ d2bf,
    float* __restrict__ posim, float* __restrict__ matchm,
    float* __restrict__ biasf, int* __restrict__ neighpk,
    unsigned int* __restrict__ negbits)
{
    __shared__ unsigned short tile[CC][65];
    int bid = blockIdx.x;
    int tid = threadIdx.x;

    if (bid < 2 * BB * 75) {
        // ---- convert fp32 [b][ch][cell] -> bf16 [b][cell][ch] ----
        int arr = bid / (BB * 75);
        int rem = bid % (BB * 75);
        int b = rem / 75;
        int t = rem % 75;
        int c0 = t * 64;
        const float* in = arr ? desc2 : desc1;
        unsigned short* out = arr ? d2bf : d1bf;
        int w = tid >> 6, l = tid & 63;
        #pragma unroll
        for (int k = 0; k < 16; k++) {
            int ch = k * 4 + w;
            tile[ch][l] = f2bf(in[((size_t)(b * CC + ch)) * NN + c0 + l]);
        }
        __syncthreads();
        #pragma unroll
        for (int k = 0; k < 16; k++) {
            int cell = k * 4 + w;
            out[((size_t)b * NN + c0 + cell) * CC + l] = tile[l][cell];
        }
        return;
    }

    // ---- per-cell: one wave per cell ----
    int sub = bid - 2 * BB * 75;          // 0..2399
    int wv = tid >> 6, lane = tid & 63;
    int idx = sub * 4 + wv;               // 0..9599
    int b = idx / NN, r = idx - b * NN;
    int ci = r / WC, cj = r - ci * WC;

    // visibility: lane = pixel (di,dj) of the 8x8 cell
    int allv;
    {
        const float* h = homo21 + b * 9;
        int di = lane >> 3, dj = lane & 7;
        float y = (float)(ci * 8 + di);
        float x = (float)(cj * 8 + dj);
        float qx = h[0]*x + h[1]*y + h[2];
        float qy = h[3]*x + h[4]*y + h[5];
        float qw = h[6]*x + h[7]*y + h[8];
        float px = qx / (qw + EPSF);
        float py = qy / (qw + EPSF);
        float y0 = floorf(py), x0 = floorf(px);
        float ty = py - y0,   tx = px - x0;
        float fyv = ((y0 >= 0.0f && y0 <= (float)(HIMG-1)) ? (1.0f-ty) : 0.0f)
                  + ((y0+1.0f >= 0.0f && y0+1.0f <= (float)(HIMG-1)) ? ty : 0.0f);
        float fxv = ((x0 >= 0.0f && x0 <= (float)(WIMG-1)) ? (1.0f-tx) : 0.0f)
                  + ((x0+1.0f >= 0.0f && x0+1.0f <= (float)(WIMG-1)) ? tx : 0.0f);
        int ok = (fyv > 0.0f && fxv > 0.0f) ? 1 : 0;
        allv = __all(ok);
    }

    // warp + bilinear setup (all lanes redundantly, uniform)
    const float* h = homo12 + b * 9;
    float xx = cj * 8.0f + 3.5f;
    float yy = ci * 8.0f + 3.5f;
    float qx = h[0]*xx + h[1]*yy + h[2];
    float qy = h[3]*xx + h[4]*yy + h[5];
    float qw = h[6]*xx + h[7]*yy + h[8];
    float wx = qx / (qw + EPSF);
    float wy = qy / (qw + EPSF);
    float dy = (wy - 4.0f + 0.5f) / 8.0f;
    float dx = (wx - 4.0f + 0.5f) / 8.0f;

    float y0f = floorf(dy), x0f = floorf(dx);
    float fy = dy - y0f, fx = dx - x0f;
    float y1f = y0f + 1.0f, x1f = x0f + 1.0f;
    bool v0y = (y0f >= 0.0f && y0f <= (float)(HC-1));
    bool v1y = (y1f >= 0.0f && y1f <= (float)(HC-1));
    bool v0x = (x0f >= 0.0f && x0f <= (float)(WC-1));
    bool v1x = (x1f >= 0.0f && x1f <= (float)(WC-1));
    float w00 = (1.0f-fy)*(1.0f-fx); if (!(v0y && v0x)) w00 = 0.0f;
    float w01 = (1.0f-fy)*fx;        if (!(v0y && v1x)) w01 = 0.0f;
    float w10 = fy*(1.0f-fx);        if (!(v1y && v0x)) w10 = 0.0f;
    float w11 = fy*fx;               if (!(v1y && v1x)) w11 = 0.0f;
    int yc0 = (int)fminf(fmaxf(y0f, 0.0f), (float)(HC-1));
    int yc1 = (int)fminf(fmaxf(y1f, 0.0f), (float)(HC-1));
    int xc0 = (int)fminf(fmaxf(x0f, 0.0f), (float)(WC-1));
    int xc1 = (int)fminf(fmaxf(x1f, 0.0f), (float)(WC-1));
    int o00 = yc0*WC + xc0, o01 = yc0*WC + xc1;
    int o10 = yc1*WC + xc0, o11 = yc1*WC + xc1;

    // lane = channel
    int ch = lane;
    const float* d2b = desc2 + (size_t)b * CC * NN;
    const float* p = d2b + ch * NN;
    float wvl = w00*p[o00] + w01*p[o01] + w10*p[o10] + w11*p[o11];
    float s2 = wvl * wvl;
    float sd = desc1[((size_t)(b * CC + ch)) * NN + r] * wvl;
    #pragma unroll
    for (int off = 1; off < 64; off <<= 1) {
        s2 += __shfl_xor(s2, off);
        sd += __shfl_xor(sd, off);
    }

    if (lane == 0) {
        biasf[idx] = allv ? 16.0f : 8.0f;
        matchm[idx] = (wy >= 0.0f && wy <= (float)(HIMG-1) &&
                       wx >= 0.0f && wx <= (float)(WIMG-1)) ? 1.0f : 0.0f;
        float dot = sd / (sqrtf(s2) + EPSF);
        posim[idx] = sqrtf(fmaxf(2.0f - 2.0f*dot, EPSF));

        // top-4 nearest grid centers -> packed bbox mask
        int i0 = (int)floorf(dy);
        int j0 = (int)floorf(dx);
        int ilo = i0 - 1; if (ilo < 0) ilo = 0; if (ilo > HC-4) ilo = HC-4;
        int jlo = j0 - 1; if (jlo < 0) jlo = 0; if (jlo > WC-4) jlo = WC-4;
        float bd0=3e38f, bd1=3e38f, bd2=3e38f, bd3=3e38f;
        int   id0=0,     id1=0,     id2=0,     id3=0;
        #pragma unroll
        for (int a = 0; a < 4; a++) {
            float cy = (float)(ilo + a) * 8.0f + 3.5f;
            float ddy = wy - cy;
            float ddy2 = ddy * ddy;
            #pragma unroll
            for (int q = 0; q < 4; q++) {
                float cx = (float)(jlo + q) * 8.0f + 3.5f;
                float ddx = wx - cx;
                float dv = ddy2 + ddx * ddx;
                int id = (ilo + a) * WC + (jlo + q);
                if (dv < bd3) {             // strict: lower index wins ties
                    bd3 = dv; id3 = id;
                    if (bd3 < bd2) { float tf=bd2; bd2=bd3; bd3=tf; int ti=id2; id2=id3; id3=ti; }
                    if (bd2 < bd1) { float tf=bd1; bd1=bd2; bd2=tf; int ti=id1; id1=id2; id2=ti; }
                    if (bd1 < bd0) { float tf=bd0; bd0=bd1; bd1=tf; int ti=id0; id0=id1; id1=ti; }
                }
            }
        }
        int base = ilo * WC + jlo;
        int mask = 0;
        {
            int d, ri, rj;
            d = id0 - base; ri = d / WC; rj = d - ri * WC; mask |= 1 << (ri*4+rj);
            d = id1 - base; ri = d / WC; rj = d - ri * WC; mask |= 1 << (ri*4+rj);
            d = id2 - base; ri = d / WC; rj = d - ri * WC; mask |= 1 << (ri*4+rj);
            d = id3 - base; ri = d / WC; rj = d - ri * WC; mask |= 1 << (ri*4+rj);
        }
        neighpk[idx] = mask | (ilo << 16) | (jlo << 24);
        negbits[idx] = 0x7F800000u;      // +inf
    }
}

// ============ k_negmin: R6 body at 1-wave blocks / 16-col tiles ============
// Identical per-wave structure and register state; block geometry only
// (64 threads, 2 KB tiles, TGN=24) -> zero inter-wave barrier coupling and
// a one-round grid packing (7200 blocks = 28.1/CU < 32-wave cap).

#define GLL(gp, lp) __builtin_amdgcn_global_load_lds(                        \
    (const __attribute__((address_space(1))) unsigned int*)(gp),             \
    (__attribute__((address_space(3))) unsigned int*)(lp), 16, 0, 0)

#define MFMA16(A, B, C) __builtin_amdgcn_mfma_f32_16x16x32_bf16((A), (B), (C), 0, 0, 0)

__global__ __launch_bounds__(64) void k_negmin(
    const unsigned short* __restrict__ d1bf, const unsigned short* __restrict__ d2bf,
    const float* __restrict__ biasf, const int* __restrict__ neighpk,
    unsigned int* __restrict__ negbits)
{
    __shared__ unsigned short Bsm[2][1024];   // 2 x 2 KB tiles (16 cols x 64 ch bf16)

    int bid = blockIdx.x;                 // BB * 150 * 24 = 7200
    int b   = bid / (150 * TGN);
    int rem = bid % (150 * TGN);
    int rb  = rem / TGN;                  // row-block 0..149
    int tg  = rem % TGN;                  // col-group 0..23
    int lane = threadIdx.x;               // 0..63 (one wave)
    int l15 = lane & 15, lg = lane >> 4;
    int r0  = rb * 32;
    int wl  = l15;                        // col within a 16-col tile
    int lg8 = lg * 8;
    int bNN = b * NN;

    const unsigned short* d1b = d1bf + (size_t)bNN * CC;
    const unsigned short* d2b = d2bf + (size_t)bNN * CC;

    short8v afr00 = *(const short8v*)(d1b + (size_t)(r0 + l15) * CC + lg8);
    short8v afr01 = *(const short8v*)(d1b + (size_t)(r0 + l15) * CC + 32 + lg8);
    short8v afr10 = *(const short8v*)(d1b + (size_t)(r0 + 16 + l15) * CC + lg8);
    short8v afr11 = *(const short8v*)(d1b + (size_t)(r0 + 16 + l15) * CC + 32 + lg8);

    int pk[8];
    int lmin = 0x7FFFFFFF, lmax = -1;
    #pragma unroll
    for (int s_ = 0; s_ < 8; s_++) {
        int row = r0 + (s_ >> 2) * 16 + lg * 4 + (s_ & 3);
        int p = neighpk[bNN + row];
        pk[s_] = p;
        int ilo = (p >> 16) & 0xFF, jlo = (p >> 24) & 0xFF;
        int idm = ilo * WC + jlo;
        lmin = min(lmin, idm);
        lmax = max(lmax, idm + 3 * WC + 3);
    }
    #pragma unroll
    for (int off = 1; off < 64; off <<= 1) {
        lmin = min(lmin, __shfl_xor(lmin, off));
        lmax = max(lmax, __shfl_xor(lmax, off));
    }

    float m[8];
    #pragma unroll
    for (int i = 0; i < 8; i++) m[i] = -BIGF;

    // staging lane constants: LDS granules o0/o1 (0..127), pre-swizzled global s0/s1
    int o0 = lane;                        // 0..63
    int o1 = lane + 64;                   // 64..127
    int s0 = (o0 & ~7) | ((o0 ^ (o0 >> 3)) & 7);
    int s1 = (o1 & ~7) | ((o1 ^ (o1 >> 3)) & 7);

    int nt = (NCT - tg + TGN - 1) / TGN;  // 13 for tg<12, else 12

    // prologue: stage first tile (granule g lives at short-offset g*8)
    {
        const unsigned short* tb0 = d2b + (size_t)(tg * 16) * CC;
        GLL(tb0 + s0 * 8, &Bsm[0][0]);
        GLL(tb0 + s1 * 8, &Bsm[0][512]);
    }
    float bias = biasf[bNN + tg * 16 + wl];
    __syncthreads();

    int buf = 0;
    for (int it = 0; it < nt; it++) {
        int t = tg + it * TGN;

        // issue next tile's stage early (hides under MFMA+epilogue; barrier drains it)
        float bias_n = 0.0f;
        if (it + 1 < nt) {
            const unsigned short* tbn = d2b + (size_t)((t + TGN) * 16) * CC;
            GLL(tbn + s0 * 8, &Bsm[buf ^ 1][0]);
            GLL(tbn + s1 * 8, &Bsm[buf ^ 1][512]);
            bias_n = biasf[bNN + (t + TGN) * 16 + wl];
        }

        // B frags from LDS (swizzled granule read; col stride = 8 granules)
        const unsigned short* lb = &Bsm[buf][0];
        short8v b0 = *(const short8v*)(lb + (size_t)wl * 64 + (size_t)((lg ^ wl) & 7) * 8);
        short8v b1 = *(const short8v*)(lb + (size_t)wl * 64 + (size_t)(((4 + lg) ^ wl) & 7) * 8);

        f32x4 a0 = {bias, bias, bias, bias};
        f32x4 a1 = a0;
        a0 = MFMA16(afr00, b0, a0);
        a0 = MFMA16(afr01, b1, a0);
        a1 = MFMA16(afr10, b0, a1);
        a1 = MFMA16(afr11, b1, a1);

        int tb = t * 16;
        if (tb + 15 < lmin || tb > lmax) {
            #pragma unroll
            for (int g_ = 0; g_ < 4; g_++) {
                m[g_]   = fmaxf(m[g_],   a0[g_]);
                m[4+g_] = fmaxf(m[4+g_], a1[g_]);
            }
        } else {
            int c_ = tb + wl;
            int gi_ = c_ / WC; int gj_ = c_ - gi_ * WC;
            #pragma unroll
            for (int s_ = 0; s_ < 8; s_++) {
                int p_ = pk[s_]; int msk_ = p_ & 0xFFFF;
                unsigned ri_ = (unsigned)(gi_ - ((p_ >> 16) & 0xFF));
                unsigned rj_ = (unsigned)(gj_ - ((p_ >> 24) & 0xFF));
                unsigned bx_ = (ri_ < 4u && rj_ < 4u) ? (ri_ * 4u + rj_) : 16u;
                bool nb_ = ((msk_ >> bx_) & 1) != 0;
                float sv_ = (s_ < 4) ? a0[s_ & 3] : a1[s_ & 3];
                float key_ = nb_ ? sv_ - 8.0f : sv_;
                m[s_] = fmaxf(m[s_], key_);
            }
        }

        bias = bias_n;
        buf ^= 1;
        __syncthreads();   // single-wave: degenerates to waitcnt (stage landed)
    }

    // finalize: decode band -> penalty, sqrt, 16-lane min-reduce, atomicMin per row
    #pragma unroll
    for (int s_ = 0; s_ < 8; s_++) {
        float mv = m[s_];
        float pen, sdot;
        if (mv >= 12.0f)     { pen = 0.0f;  sdot = mv - 16.0f; }
        else if (mv >= 4.0f) { pen = 5.0f;  sdot = mv - 8.0f; }
        else                 { pen = 10.0f; sdot = mv; }
        float res = sqrtf(fmaxf(2.0f - 2.0f * sdot, EPSF)) + pen;
        #pragma unroll
        for (int off = 1; off < 16; off <<= 1)
            res = fminf(res, __shfl_xor(res, off));
        if (l15 == 0) {
            int row = r0 + (s_ >> 2) * 16 + lg * 4 + (s_ & 3);
            atomicMin(&negbits[bNN + row], __float_as_uint(res));
        }
    }
}

// ============ per-row loss partials (38 blocks) + final sum ============
__global__ void k_loss(const float* __restrict__ posim, const float* __restrict__ matchm,
                       const unsigned int* __restrict__ negbits, float* __restrict__ bpart)
{
    __shared__ float sn[256], sdn[256];
    int tid = threadIdx.x;
    int idx = blockIdx.x * 256 + tid;
    float num = 0.0f, den = 0.0f;
    if (idx < BB * NN) {
        float neg = __uint_as_float(negbits[idx]);
        float l = fmaxf(posim[idx] - neg + 1.0f, 0.0f);
        float mm = matchm[idx];
        num = l * l * mm;
        den = mm;
    }
    sn[tid] = num; sdn[tid] = den;
    __syncthreads();
    for (int st = 128; st > 0; st >>= 1) {
        if (tid < st) { sn[tid] += sn[tid + st]; sdn[tid] += sdn[tid + st]; }
        __syncthreads();
    }
    if (tid == 0) { bpart[blockIdx.x * 2] = sn[0]; bpart[blockIdx.x * 2 + 1] = sdn[0]; }
}

__global__ void k_sum(const float* __restrict__ bpart, int nb, float* __restrict__ out)
{
    int t = threadIdx.x;
    float num = 0.0f, den = 0.0f;
    if (t < nb) { num = bpart[t * 2]; den = bpart[t * 2 + 1]; }
    #pragma unroll
    for (int off = 1; off < 64; off <<= 1) {
        num += __shfl_xor(num, off);
        den += __shfl_xor(den, off);
    }
    if (t == 0) out[0] = num / den;
}

extern "C" void kernel_launch(void* const* d_in, const int* in_sizes, int n_in,
                              void* d_out, int out_size, void* d_ws, size_t ws_size,
                              hipStream_t stream)
{
    const float* desc1  = (const float*)d_in[2];
    const float* desc2  = (const float*)d_in[3];
    const float* homo12 = (const float*)d_in[4];
    const float* homo21 = (const float*)d_in[5];
    float* out = (float*)d_out;

    float*        biasf   = (float*)d_ws;                      // 9600
    float*        posim   = biasf + BB * NN;                   // 9600
    float*        matchm  = posim + BB * NN;                   // 9600
    int*          neighpk = (int*)(matchm + BB * NN);          // 9600
    unsigned int* negbits = (unsigned int*)(neighpk + BB * NN);// 9600
    float*        bpart   = (float*)(negbits + BB * NN);       // 128
    unsigned short* d1bf  = (unsigned short*)(bpart + 128);
    unsigned short* d2bf  = d1bf + (size_t)BB * NN * CC;

    int nb = (BB * NN + 255) / 256;                            // 38
    int nb_pre = 2 * BB * 75 + 2 * BB * 75 * 4;                // 300 cvt + 2400 percell
    k_pre<<<nb_pre, 256, 0, stream>>>(desc1, desc2, homo12, homo21,
                                      d1bf, d2bf, posim, matchm, biasf, neighpk, negbits);
    k_negmin<<<BB * 150 * TGN, 64, 0, stream>>>(d1bf, d2bf, biasf, neighpk, negbits);
    k_loss<<<nb, 256, 0, stream>>>(posim, matchm, negbits, bpart);
    k_sum<<<1, 64, 0, stream>>>(bpart, nb, out);
}